// Round 3
// baseline (6108.201 us; speedup 1.0000x reference)
//
#include <hip/hip_runtime.h>
#include <cstdint>
#include <cstddef>

// SimpleRNN: B=4096, K=512, U=3, P=5, LIFT=32, HID=128, NSUB=10
// Round 6: independent-stream overlap. Round-2 result showed the kernel is a
// latency-bound serial scan (per-step chain ~6.7k cycles, VALU/MFMA issue both
// <10% static): more waves in the SAME block didn't help (barrier-locked).
// This round: BB=8 batches/block, 512 blocks -> 2 INDEPENDENT blocks per CU
// (16 waves/CU). Two serial chains interleave on each CU. MFMA rows 8-15 ride
// empty (junk confined to unread C rows; all LDS zero-initialized -> no NaNs).
// Phase structure identical to round 2 for clean attribution.

#define KTOT 512
#define BB   16    // LDS row capacity (MFMA geometry); real batches per block = 8
#define BR   8     // real batches per block

typedef _Float16 half8 __attribute__((ext_vector_type(8)));
typedef float    f32x4 __attribute__((ext_vector_type(4)));

struct __align__(16) Smem {
  _Float16 hf16[BB][136];   // f16 hidden (A-frag source)
  _Float16 xls[BB][32];     // f16 lift output (A-frag source)
  float brz[256];           // b_ih + b_hh for r,z
  float bnx[128];           // b_ih n-gate
  float bnh[128];           // b_hh n-gate
  float bhv[16];
  float theta[BB][14];
  float yst[BB][8];
  float ust[2][BB][4];      // double-buffered u
  float dtst[2][BB];        // double-buffered dt
};

__device__ __forceinline__ float sigm(float x)     { return 1.f / (1.f + __expf(-x)); }
__device__ __forceinline__ float tanhfast(float x) { return 1.f - 2.f / (1.f + __expf(2.f * x)); }

template<int CTRL>
__device__ __forceinline__ float dppf(float x) {
  return __int_as_float(__builtin_amdgcn_mov_dpp(__float_as_int(x), CTRL, 0xf, 0xf, true));
}
#define QP_PLUS  0x39   // quad_perm [1,2,3,0]
#define QP_MINUS 0x93   // quad_perm [3,0,1,2]
#define QB0 0x00
#define QB1 0x55
#define QB2 0xAA
#define QB3 0xFF

// Y = I + ALPHA * Z * X   (row-per-lane; lane3 also owns row4 in X4r/Y4r)
#define MATMUL(Yr, Y4r, Xr, X4r, ALPHA) do {                                  \
  float xm_[5], xp_[5];                                                       \
  _Pragma("unroll")                                                           \
  for (int j_ = 0; j_ < 5; j_++) {                                            \
    xm_[j_] = dppf<QP_MINUS>(Xr[j_]);                                         \
    xp_[j_] = dppf<QP_PLUS >(Xr[j_]);                                         \
  }                                                                           \
  _Pragma("unroll")                                                           \
  for (int j_ = 0; j_ < 5; j_++) {                                            \
    const float ac_ = Zl*xm_[j_] + Zd*Xr[j_] + Zu*xp_[j_] + Zu4*X4r[j_];      \
    const float a4_ = Z43*Xr[j_] + Z44*X4r[j_];                               \
    Yr[j_]  = ((j_ == s_) ? 1.f : 0.f) + (ALPHA)*ac_;                         \
    Y4r[j_] = ((j_ == 4 ) ? 1.f : 0.f) + (ALPHA)*a4_;                         \
  } } while (0)

__global__ __launch_bounds__(512, 4) void rnn_scan_kernel(
    const float* __restrict__ y0,    const float* __restrict__ u_seq,
    const float* __restrict__ dt_sq, const float* __restrict__ Wl,
    const float* __restrict__ bl,    const float* __restrict__ W_ih,
    const float* __restrict__ b_ih,  const float* __restrict__ W_hh,
    const float* __restrict__ b_hh,  const float* __restrict__ Wh,
    const float* __restrict__ bh,    const float* __restrict__ jmp,
    float* __restrict__ y_out, float* __restrict__ th_out)
{
  __shared__ Smem sm;
  const int t   = threadIdx.x;
  const int w   = t >> 6;          // 0..7
  const int l   = t & 63;
  const int n16 = l & 15;
  const int q   = l >> 4;
  const int B0  = blockIdx.x * BR;

  // ---------------- one-time init (rows >= BR zero-filled everywhere) ----------------
  if (t < 256) sm.brz[t] = b_ih[t] + b_hh[t];
  if (t < 128) { sm.bnx[t] = b_ih[256+t]; sm.bnh[t] = b_hh[256+t]; }
  if (t < 16)  sm.bhv[t] = (t < 13) ? bh[t] : 0.f;
  if (t >= 256 && t < 384) { const int b = (t-256) >> 3, i = (t-256) & 7;
    sm.yst[b][i] = (i < 5 && b < BR) ? (y0[(size_t)(B0+b)*5 + i] + 0.01f) : 0.f; }
  if (t >= 384 && t < 432) { const int idx = t-384, b = idx/3, c = idx - (idx/3)*3;
    sm.ust[0][b][c] = (b < BR) ? u_seq[((size_t)(B0+b)*KTOT + 0)*3 + c] : 0.f;
    sm.ust[0][b][3] = 0.f;
    sm.ust[1][b][c] = 0.f;  sm.ust[1][b][3] = 0.f; }
  if (t >= 432 && t < 448) { const int b = t-432;
    sm.dtst[0][b] = (b < BR) ? dt_sq[(size_t)(B0+b)*KTOT + 0] : 0.f;
    sm.dtst[1][b] = 0.f; }

  // lift: one output per thread; Wl column pinned in VGPRs (loop-invariant)
  const int lb = t >> 5;           // batch row 0..15 (rows >= BR are zero-data)
  const int lo = t & 31;           // lift out col 0..31
  float wlc[8];
  #pragma unroll
  for (int c = 0; c < 8; c++) wlc[c] = Wl[lo*8 + c];
  const float blv = bl[lo];

  // head B-frags (wave0 use)
  half8 whf[4];
  #pragma unroll
  for (int ks = 0; ks < 4; ks++)
    #pragma unroll
    for (int i = 0; i < 8; i++) {
      const int kk = ks*32 + q*8 + i;
      whf[ks][i] = (n16 < 13) ? (_Float16)Wh[n16*128 + kk] : (_Float16)0.f;
    }

  // GRU weight fragments: this wave's single 16-col slice
  const int jR = w*16 + n16;
  const int jZ = jR + 128, jN = jR + 256;
  half8 wihR, wihZ, wihN, whhR[4], whhZ[4], whhN[4];
  #pragma unroll
  for (int i = 0; i < 8; i++) {
    const int kk = q*8 + i;
    wihR[i] = (_Float16)W_ih[jR*32 + kk];
    wihZ[i] = (_Float16)W_ih[jZ*32 + kk];
    wihN[i] = (_Float16)W_ih[jN*32 + kk];
  }
  #pragma unroll
  for (int ks = 0; ks < 4; ks++)
    #pragma unroll
    for (int i = 0; i < 8; i++) {
      const int kk = ks*32 + q*8 + i;
      whhR[ks][i] = (_Float16)W_hh[jR*128 + kk];
      whhZ[ks][i] = (_Float16)W_hh[jZ*128 + kk];
      whhN[ks][i] = (_Float16)W_hh[jN*128 + kk];
    }

  float hreg[4] = {0.f, 0.f, 0.f, 0.f};
  const f32x4 zero4 = {0.f, 0.f, 0.f, 0.f};
  f32x4 accPreR = zero4, accPreZ = zero4, accPreN = zero4;   // h-GEMM partials

  // RK4 lane mapping (wave0): lane = b4*4 + s_ (rows >= BR compute on zero data)
  const int s_ = l & 3, b4 = l >> 2;
  const float jr0 = jmp[0*5 + s_], jr1 = jmp[1*5 + s_], jr2 = jmp[2*5 + s_];
  const float j40 = (s_==3) ? jmp[4]  : 0.f;
  const float j41 = (s_==3) ? jmp[9]  : 0.f;
  const float j42 = (s_==3) ? jmp[14] : 0.f;

  // output store mappings (disjoint thread ranges; BR batches only)
  const int yb = (t/5) & 7, yi = t - (t/5)*5;          // t < 40
  float* yo_base = y_out + ((size_t)(B0 + yb)*KTOT)*5 + yi;
  const int ts = (t >= 64) ? (t - 64) : 0;             // t in [64, 168)
  const int tb = (ts/13) & 7, tn = ts - (ts/13)*13;
  float* th_base = th_out + ((size_t)(B0 + tb)*KTOT)*13 + tn;
  // u-prefetch mapping (wave1)
  const int upb = l/3, upc = l - (l/3)*3;              // l < 24

  __syncthreads();

  // hoist loop-invariant LDS biases into registers (legal: after the init barrier)
  const float br  = sm.brz[jR];
  const float bz  = sm.brz[128 + jR];
  const float bx  = sm.bnx[jR];
  const float bn  = sm.bnh[jR];
  const float bb_ = sm.bhv[n16];

  #pragma unroll 1
  for (int k = 0; k < KTOT; k++) {
    const int buf  = k & 1;
    const int nbuf = (k + 1) & 1;
    const int kp   = (k + 1 < KTOT) ? (k + 1) : (KTOT - 1);

    // ---- phase LIFT: one silu(feat.Wl) value per thread ----
    {
      const f32x4 uu = *(const f32x4*)&sm.ust[buf][lb][0];
      const f32x4 ya = *(const f32x4*)&sm.yst[lb][0];
      const f32x4 yc = *(const f32x4*)&sm.yst[lb][4];
      const float a = blv
        + uu[0]*wlc[0] + uu[1]*wlc[1] + uu[2]*wlc[2]
        + ya[0]*wlc[3] + ya[1]*wlc[4] + ya[2]*wlc[5] + ya[3]*wlc[6]
        + yc[0]*wlc[7];
      sm.xls[lb][lo] = (_Float16)(a * sigm(a));
    }
    __syncthreads();

    // ---- phase GATE: x-part MFMAs + activations ----
    if (k > 0) {               // stores of step k-1 drain under gate compute
      if (t < 40)                     yo_base[(size_t)(k-1)*5]  = sm.yst[yb][yi];
      else if (t >= 64 && t < 168)    th_base[(size_t)(k-1)*13] = sm.theta[tb][tn];
    }
    {
      const half8 xf = *(const half8*)&sm.xls[n16][q*8];
      const f32x4 accR  = __builtin_amdgcn_mfma_f32_16x16x32_f16(xf, wihR, accPreR, 0,0,0);
      const f32x4 accZ  = __builtin_amdgcn_mfma_f32_16x16x32_f16(xf, wihZ, accPreZ, 0,0,0);
      const f32x4 accXN = __builtin_amdgcn_mfma_f32_16x16x32_f16(xf, wihN, zero4,   0,0,0);
      #pragma unroll
      for (int rg = 0; rg < 4; rg++) {
        const float r  = sigm(accR[rg] + br);
        const float z  = sigm(accZ[rg] + bz);
        const float nn = tanhfast(accXN[rg] + bx + r*(accPreN[rg] + bn));
        const float ho = hreg[rg];
        const float hn = nn + z*(ho - nn);
        hreg[rg] = hn;
        sm.hf16[q*4 + rg][jR] = (_Float16)hn;
      }
    }
    __syncthreads();

    // ---- phase CD: h-GEMM for step k+1  ||  wave0: head + theta + RK4 ----
    float pref_u = 0.f, pref_dt = 0.f;
    if (w == 1 && l < 24)
      pref_u = u_seq[((size_t)(B0 + upb)*KTOT + kp)*3 + upc];
    if (w == 2 && l < 8)
      pref_dt = dt_sq[(size_t)(B0 + l)*KTOT + kp];

    half8 hfrag[4];
    #pragma unroll
    for (int ks = 0; ks < 4; ks++)
      hfrag[ks] = *(const half8*)&sm.hf16[n16][ks*32 + q*8];

    accPreR = zero4; accPreZ = zero4; accPreN = zero4;
    #pragma unroll
    for (int ks = 0; ks < 4; ks++) {
      accPreR = __builtin_amdgcn_mfma_f32_16x16x32_f16(hfrag[ks], whhR[ks], accPreR, 0,0,0);
      accPreZ = __builtin_amdgcn_mfma_f32_16x16x32_f16(hfrag[ks], whhZ[ks], accPreZ, 0,0,0);
      accPreN = __builtin_amdgcn_mfma_f32_16x16x32_f16(hfrag[ks], whhN[ks], accPreN, 0,0,0);
    }

    if (w == 0) {
      // head -> theta
      f32x4 accH = zero4;
      #pragma unroll
      for (int ks = 0; ks < 4; ks++)
        accH = __builtin_amdgcn_mfma_f32_16x16x32_f16(hfrag[ks], whf[ks], accH, 0,0,0);
      #pragma unroll
      for (int rg = 0; rg < 4; rg++) {
        const float sg  = sigm(accH[rg] + bb_);
        const float thv = (n16 < 8) ? (0.01f + 2.99f*sg) : (0.3f*sg);
        if (n16 < 13) sm.theta[q*4 + rg][n16] = thv;
      }
      // ---- exact-linear RK4 (ds ops in-order within wave: theta writes land first) ----
      const float* th = sm.theta[b4];
      const float dt = sm.dtst[buf][b4];
      const float h  = dt * 0.1f;
      const float thm = th[s_ ? (s_ - 1) : 0];
      const float Zl  = s_ ? h*thm : 0.f;
      const float krs = s_ ? th[3 + s_] : 0.f;
      const float Zd  = -h*(th[s_] + krs);
      const float Zur = h*th[4 + s_];
      const float Zu  = (s_ < 3) ? Zur : 0.f;
      const float Zu4 = (s_ == 3) ? Zur : 0.f;
      const float Z43 = h*th[3];
      const float Z44 = -h*th[7];
      const float c0 = th[8], c1 = th[9], c2 = th[10], c3 = th[11], c4 = th[12];
      float Xa[5], Xa4[5], Xb[5], Xb4[5];
      #pragma unroll
      for (int j = 0; j < 5; j++) {
        const float zr = (j == s_) ? Zd : ((j == s_ + 1) ? Zur : ((j + 1 == s_) ? Zl : 0.f));
        Xa[j] = ((j == s_) ? 1.f : 0.f) + 0.25f*zr;
      }
      Xa4[0] = 0.f; Xa4[1] = 0.f; Xa4[2] = 0.f;
      Xa4[3] = 0.25f*Z43; Xa4[4] = 1.f + 0.25f*Z44;
      MATMUL(Xb, Xb4, Xa, Xa4, (1.f/3.f));   // X2 = I + (Z/3) X1
      MATMUL(Xa, Xa4, Xb, Xb4, 0.5f);        // X3 = S = I + (Z/2) X2
      const float bv  = h*(Xa[0]*c0 + Xa[1]*c1 + Xa[2]*c2 + Xa[3]*c3 + Xa[4]*c4);
      const float bv4 = h*(Xa4[0]*c0 + Xa4[1]*c1 + Xa4[2]*c2 + Xa4[3]*c3 + Xa4[4]*c4);
      MATMUL(Xb, Xb4, Xa, Xa4, 1.f);         // A = I + Z S
      const float uu0 = sm.ust[buf][b4][0], uu1 = sm.ust[buf][b4][1], uu2 = sm.ust[buf][b4][2];
      float y  = sm.yst[b4][s_] + uu0*jr0 + uu1*jr1 + uu2*jr2;
      float y4 = sm.yst[b4][4]  + uu0*j40 + uu1*j41 + uu2*j42;
      #pragma unroll
      for (int ss = 0; ss < 10; ss++) {
        const float v0 = dppf<QB0>(y), v1 = dppf<QB1>(y),
                    v2 = dppf<QB2>(y), v3 = dppf<QB3>(y);
        const float v4 = dppf<QB3>(y4);
        const float yn  = fmaxf(bv  + Xb[0]*v0 + Xb[1]*v1 + Xb[2]*v2 + Xb[3]*v3 + Xb[4]*v4, 0.f);
        const float y4n = fmaxf(bv4 + Xb4[0]*v0 + Xb4[1]*v1 + Xb4[2]*v2 + Xb4[3]*v3 + Xb4[4]*v4, 0.f);
        y = yn; y4 = y4n;
      }
      sm.yst[b4][s_] = y;
      if (s_ == 3) sm.yst[b4][4] = y4;
    }
    // land prefetch into LDS (loads have had the whole phase to complete)
    if (w == 1 && l < 24) sm.ust[nbuf][upb][upc] = pref_u;
    if (w == 2 && l < 8)  sm.dtst[nbuf][l] = pref_dt;
    __syncthreads();
  }

  // epilogue: stores for step KTOT-1
  if (t < 40)                   yo_base[(size_t)(KTOT-1)*5]  = sm.yst[yb][yi];
  else if (t >= 64 && t < 168)  th_base[(size_t)(KTOT-1)*13] = sm.theta[tb][tn];
}

extern "C" void kernel_launch(void* const* d_in, const int* in_sizes, int n_in,
                              void* d_out, int out_size, void* d_ws, size_t ws_size,
                              hipStream_t stream) {
  const float* y0     = (const float*)d_in[0];
  const float* u_seq  = (const float*)d_in[1];
  const float* dt_sq  = (const float*)d_in[2];
  const float* Wl     = (const float*)d_in[3];
  const float* bl     = (const float*)d_in[4];
  const float* W_ih   = (const float*)d_in[5];
  const float* b_ih   = (const float*)d_in[6];
  const float* W_hh   = (const float*)d_in[7];
  const float* b_hh   = (const float*)d_in[8];
  const float* Wh     = (const float*)d_in[9];
  const float* bh     = (const float*)d_in[10];
  const float* jmp    = (const float*)d_in[11];
  float* y_out  = (float*)d_out;
  float* th_out = y_out + (size_t)4096 * KTOT * 5;   // y (B,K,5) then theta (B,K,13)
  rnn_scan_kernel<<<512, 512, 0, stream>>>(
      y0, u_seq, dt_sq, Wl, bl, W_ih, b_ih, W_hh, b_hh, Wh, bh, jmp, y_out, th_out);
}

// Round 5
// 2656.507 us; speedup vs baseline: 2.2993x; 2.2993x over previous
//
#include <hip/hip_runtime.h>
#include <cstdint>
#include <cstddef>

// SimpleRNN: B=4096, K=512, U=3, P=5, LIFT=32, HID=128, NSUB=10
// Round 8: resubmission of round-7 (infra failure, no perf signal).
// Structure: BB=8 real batches/block, 512 blocks -> 2 independent blocks/CU
// (16 waves/CU), __launch_bounds__(512,2) so the ~112-VGPR working set does
// NOT spill (round-6's (512,4) capped at 64 VGPR -> 14 GB of scratch traffic).
// Two barrier-decoupled serial scan chains interleave per CU.

#define KTOT 512
#define BB   16    // LDS row capacity (MFMA geometry); real batches per block = 8
#define BR   8     // real batches per block

typedef _Float16 half8 __attribute__((ext_vector_type(8)));
typedef float    f32x4 __attribute__((ext_vector_type(4)));

struct __align__(16) Smem {
  _Float16 hf16[BB][136];   // f16 hidden (A-frag source)
  _Float16 xls[BB][32];     // f16 lift output (A-frag source)
  float brz[256];           // b_ih + b_hh for r,z
  float bnx[128];           // b_ih n-gate
  float bnh[128];           // b_hh n-gate
  float bhv[16];
  float theta[BB][14];
  float yst[BB][8];
  float ust[2][BB][4];      // double-buffered u
  float dtst[2][BB];        // double-buffered dt
};

__device__ __forceinline__ float sigm(float x)     { return 1.f / (1.f + __expf(-x)); }
__device__ __forceinline__ float tanhfast(float x) { return 1.f - 2.f / (1.f + __expf(2.f * x)); }

template<int CTRL>
__device__ __forceinline__ float dppf(float x) {
  return __int_as_float(__builtin_amdgcn_mov_dpp(__float_as_int(x), CTRL, 0xf, 0xf, true));
}
#define QP_PLUS  0x39   // quad_perm [1,2,3,0]
#define QP_MINUS 0x93   // quad_perm [3,0,1,2]
#define QB0 0x00
#define QB1 0x55
#define QB2 0xAA
#define QB3 0xFF

// Y = I + ALPHA * Z * X   (row-per-lane; lane3 also owns row4 in X4r/Y4r)
#define MATMUL(Yr, Y4r, Xr, X4r, ALPHA) do {                                  \
  float xm_[5], xp_[5];                                                       \
  _Pragma("unroll")                                                           \
  for (int j_ = 0; j_ < 5; j_++) {                                            \
    xm_[j_] = dppf<QP_MINUS>(Xr[j_]);                                         \
    xp_[j_] = dppf<QP_PLUS >(Xr[j_]);                                         \
  }                                                                           \
  _Pragma("unroll")                                                           \
  for (int j_ = 0; j_ < 5; j_++) {                                            \
    const float ac_ = Zl*xm_[j_] + Zd*Xr[j_] + Zu*xp_[j_] + Zu4*X4r[j_];      \
    const float a4_ = Z43*Xr[j_] + Z44*X4r[j_];                               \
    Yr[j_]  = ((j_ == s_) ? 1.f : 0.f) + (ALPHA)*ac_;                         \
    Y4r[j_] = ((j_ == 4 ) ? 1.f : 0.f) + (ALPHA)*a4_;                         \
  } } while (0)

__global__ __launch_bounds__(512, 2) void rnn_scan_kernel(
    const float* __restrict__ y0,    const float* __restrict__ u_seq,
    const float* __restrict__ dt_sq, const float* __restrict__ Wl,
    const float* __restrict__ bl,    const float* __restrict__ W_ih,
    const float* __restrict__ b_ih,  const float* __restrict__ W_hh,
    const float* __restrict__ b_hh,  const float* __restrict__ Wh,
    const float* __restrict__ bh,    const float* __restrict__ jmp,
    float* __restrict__ y_out, float* __restrict__ th_out)
{
  __shared__ Smem sm;
  const int t   = threadIdx.x;
  const int w   = t >> 6;          // 0..7
  const int l   = t & 63;
  const int n16 = l & 15;
  const int q   = l >> 4;
  const int B0  = blockIdx.x * BR;

  // ---------------- one-time init (rows >= BR zero-filled everywhere) ----------------
  if (t < 256) sm.brz[t] = b_ih[t] + b_hh[t];
  if (t < 128) { sm.bnx[t] = b_ih[256+t]; sm.bnh[t] = b_hh[256+t]; }
  if (t < 16)  sm.bhv[t] = (t < 13) ? bh[t] : 0.f;
  if (t >= 256 && t < 384) { const int b = (t-256) >> 3, i = (t-256) & 7;
    sm.yst[b][i] = (i < 5 && b < BR) ? (y0[(size_t)(B0+b)*5 + i] + 0.01f) : 0.f; }
  if (t >= 384 && t < 432) { const int idx = t-384, b = idx/3, c = idx - (idx/3)*3;
    sm.ust[0][b][c] = (b < BR) ? u_seq[((size_t)(B0+b)*KTOT + 0)*3 + c] : 0.f;
    sm.ust[0][b][3] = 0.f;
    sm.ust[1][b][c] = 0.f;  sm.ust[1][b][3] = 0.f; }
  if (t >= 432 && t < 448) { const int b = t-432;
    sm.dtst[0][b] = (b < BR) ? dt_sq[(size_t)(B0+b)*KTOT + 0] : 0.f;
    sm.dtst[1][b] = 0.f; }

  // lift: one output per thread; Wl column pinned in VGPRs (loop-invariant)
  const int lb = t >> 5;           // batch row 0..15 (rows >= BR are zero-data)
  const int lo = t & 31;           // lift out col 0..31
  float wlc[8];
  #pragma unroll
  for (int c = 0; c < 8; c++) wlc[c] = Wl[lo*8 + c];
  const float blv = bl[lo];

  // head B-frags (wave0 use)
  half8 whf[4];
  #pragma unroll
  for (int ks = 0; ks < 4; ks++)
    #pragma unroll
    for (int i = 0; i < 8; i++) {
      const int kk = ks*32 + q*8 + i;
      whf[ks][i] = (n16 < 13) ? (_Float16)Wh[n16*128 + kk] : (_Float16)0.f;
    }

  // GRU weight fragments: this wave's single 16-col slice
  const int jR = w*16 + n16;
  const int jZ = jR + 128, jN = jR + 256;
  half8 wihR, wihZ, wihN, whhR[4], whhZ[4], whhN[4];
  #pragma unroll
  for (int i = 0; i < 8; i++) {
    const int kk = q*8 + i;
    wihR[i] = (_Float16)W_ih[jR*32 + kk];
    wihZ[i] = (_Float16)W_ih[jZ*32 + kk];
    wihN[i] = (_Float16)W_ih[jN*32 + kk];
  }
  #pragma unroll
  for (int ks = 0; ks < 4; ks++)
    #pragma unroll
    for (int i = 0; i < 8; i++) {
      const int kk = ks*32 + q*8 + i;
      whhR[ks][i] = (_Float16)W_hh[jR*128 + kk];
      whhZ[ks][i] = (_Float16)W_hh[jZ*128 + kk];
      whhN[ks][i] = (_Float16)W_hh[jN*128 + kk];
    }

  float hreg[4] = {0.f, 0.f, 0.f, 0.f};
  const f32x4 zero4 = {0.f, 0.f, 0.f, 0.f};
  f32x4 accPreR = zero4, accPreZ = zero4, accPreN = zero4;   // h-GEMM partials

  // RK4 lane mapping (wave0): lane = b4*4 + s_ (rows >= BR compute on zero data)
  const int s_ = l & 3, b4 = l >> 2;
  const float jr0 = jmp[0*5 + s_], jr1 = jmp[1*5 + s_], jr2 = jmp[2*5 + s_];
  const float j40 = (s_==3) ? jmp[4]  : 0.f;
  const float j41 = (s_==3) ? jmp[9]  : 0.f;
  const float j42 = (s_==3) ? jmp[14] : 0.f;

  // output store mappings (disjoint thread ranges; BR batches only)
  const int yb = (t/5) & 7, yi = t - (t/5)*5;          // t < 40
  float* yo_base = y_out + ((size_t)(B0 + yb)*KTOT)*5 + yi;
  const int ts = (t >= 64) ? (t - 64) : 0;             // t in [64, 168)
  const int tb = (ts/13) & 7, tn = ts - (ts/13)*13;
  float* th_base = th_out + ((size_t)(B0 + tb)*KTOT)*13 + tn;
  // u-prefetch mapping (wave1)
  const int upb = l/3, upc = l - (l/3)*3;              // l < 24

  __syncthreads();

  // hoist loop-invariant LDS biases into registers (legal: after the init barrier)
  const float br  = sm.brz[jR];
  const float bz  = sm.brz[128 + jR];
  const float bx  = sm.bnx[jR];
  const float bn  = sm.bnh[jR];
  const float bb_ = sm.bhv[n16];

  #pragma unroll 1
  for (int k = 0; k < KTOT; k++) {
    const int buf  = k & 1;
    const int nbuf = (k + 1) & 1;
    const int kp   = (k + 1 < KTOT) ? (k + 1) : (KTOT - 1);

    // ---- phase LIFT: one silu(feat.Wl) value per thread ----
    {
      const f32x4 uu = *(const f32x4*)&sm.ust[buf][lb][0];
      const f32x4 ya = *(const f32x4*)&sm.yst[lb][0];
      const f32x4 yc = *(const f32x4*)&sm.yst[lb][4];
      const float a = blv
        + uu[0]*wlc[0] + uu[1]*wlc[1] + uu[2]*wlc[2]
        + ya[0]*wlc[3] + ya[1]*wlc[4] + ya[2]*wlc[5] + ya[3]*wlc[6]
        + yc[0]*wlc[7];
      sm.xls[lb][lo] = (_Float16)(a * sigm(a));
    }
    __syncthreads();

    // ---- phase GATE: x-part MFMAs + activations ----
    if (k > 0) {               // stores of step k-1 drain under gate compute
      if (t < 40)                     yo_base[(size_t)(k-1)*5]  = sm.yst[yb][yi];
      else if (t >= 64 && t < 168)    th_base[(size_t)(k-1)*13] = sm.theta[tb][tn];
    }
    {
      const half8 xf = *(const half8*)&sm.xls[n16][q*8];
      const f32x4 accR  = __builtin_amdgcn_mfma_f32_16x16x32_f16(xf, wihR, accPreR, 0,0,0);
      const f32x4 accZ  = __builtin_amdgcn_mfma_f32_16x16x32_f16(xf, wihZ, accPreZ, 0,0,0);
      const f32x4 accXN = __builtin_amdgcn_mfma_f32_16x16x32_f16(xf, wihN, zero4,   0,0,0);
      #pragma unroll
      for (int rg = 0; rg < 4; rg++) {
        const float r  = sigm(accR[rg] + br);
        const float z  = sigm(accZ[rg] + bz);
        const float nn = tanhfast(accXN[rg] + bx + r*(accPreN[rg] + bn));
        const float ho = hreg[rg];
        const float hn = nn + z*(ho - nn);
        hreg[rg] = hn;
        sm.hf16[q*4 + rg][jR] = (_Float16)hn;
      }
    }
    __syncthreads();

    // ---- phase CD: h-GEMM for step k+1  ||  wave0: head + theta + RK4 ----
    float pref_u = 0.f, pref_dt = 0.f;
    if (w == 1 && l < 24)
      pref_u = u_seq[((size_t)(B0 + upb)*KTOT + kp)*3 + upc];
    if (w == 2 && l < 8)
      pref_dt = dt_sq[(size_t)(B0 + l)*KTOT + kp];

    half8 hfrag[4];
    #pragma unroll
    for (int ks = 0; ks < 4; ks++)
      hfrag[ks] = *(const half8*)&sm.hf16[n16][ks*32 + q*8];

    accPreR = zero4; accPreZ = zero4; accPreN = zero4;
    #pragma unroll
    for (int ks = 0; ks < 4; ks++) {
      accPreR = __builtin_amdgcn_mfma_f32_16x16x32_f16(hfrag[ks], whhR[ks], accPreR, 0,0,0);
      accPreZ = __builtin_amdgcn_mfma_f32_16x16x32_f16(hfrag[ks], whhZ[ks], accPreZ, 0,0,0);
      accPreN = __builtin_amdgcn_mfma_f32_16x16x32_f16(hfrag[ks], whhN[ks], accPreN, 0,0,0);
    }

    if (w == 0) {
      // head -> theta
      f32x4 accH = zero4;
      #pragma unroll
      for (int ks = 0; ks < 4; ks++)
        accH = __builtin_amdgcn_mfma_f32_16x16x32_f16(hfrag[ks], whf[ks], accH, 0,0,0);
      #pragma unroll
      for (int rg = 0; rg < 4; rg++) {
        const float sg  = sigm(accH[rg] + bb_);
        const float thv = (n16 < 8) ? (0.01f + 2.99f*sg) : (0.3f*sg);
        if (n16 < 13) sm.theta[q*4 + rg][n16] = thv;
      }
      // ---- exact-linear RK4 (ds ops in-order within wave: theta writes land first) ----
      const float* th = sm.theta[b4];
      const float dt = sm.dtst[buf][b4];
      const float h  = dt * 0.1f;
      const float thm = th[s_ ? (s_ - 1) : 0];
      const float Zl  = s_ ? h*thm : 0.f;
      const float krs = s_ ? th[3 + s_] : 0.f;
      const float Zd  = -h*(th[s_] + krs);
      const float Zur = h*th[4 + s_];
      const float Zu  = (s_ < 3) ? Zur : 0.f;
      const float Zu4 = (s_ == 3) ? Zur : 0.f;
      const float Z43 = h*th[3];
      const float Z44 = -h*th[7];
      const float c0 = th[8], c1 = th[9], c2 = th[10], c3 = th[11], c4 = th[12];
      float Xa[5], Xa4[5], Xb[5], Xb4[5];
      #pragma unroll
      for (int j = 0; j < 5; j++) {
        const float zr = (j == s_) ? Zd : ((j == s_ + 1) ? Zur : ((j + 1 == s_) ? Zl : 0.f));
        Xa[j] = ((j == s_) ? 1.f : 0.f) + 0.25f*zr;
      }
      Xa4[0] = 0.f; Xa4[1] = 0.f; Xa4[2] = 0.f;
      Xa4[3] = 0.25f*Z43; Xa4[4] = 1.f + 0.25f*Z44;
      MATMUL(Xb, Xb4, Xa, Xa4, (1.f/3.f));   // X2 = I + (Z/3) X1
      MATMUL(Xa, Xa4, Xb, Xb4, 0.5f);        // X3 = S = I + (Z/2) X2
      const float bv  = h*(Xa[0]*c0 + Xa[1]*c1 + Xa[2]*c2 + Xa[3]*c3 + Xa[4]*c4);
      const float bv4 = h*(Xa4[0]*c0 + Xa4[1]*c1 + Xa4[2]*c2 + Xa4[3]*c3 + Xa4[4]*c4);
      MATMUL(Xb, Xb4, Xa, Xa4, 1.f);         // A = I + Z S
      const float uu0 = sm.ust[buf][b4][0], uu1 = sm.ust[buf][b4][1], uu2 = sm.ust[buf][b4][2];
      float y  = sm.yst[b4][s_] + uu0*jr0 + uu1*jr1 + uu2*jr2;
      float y4 = sm.yst[b4][4]  + uu0*j40 + uu1*j41 + uu2*j42;
      #pragma unroll
      for (int ss = 0; ss < 10; ss++) {
        const float v0 = dppf<QB0>(y), v1 = dppf<QB1>(y),
                    v2 = dppf<QB2>(y), v3 = dppf<QB3>(y);
        const float v4 = dppf<QB3>(y4);
        const float yn  = fmaxf(bv  + Xb[0]*v0 + Xb[1]*v1 + Xb[2]*v2 + Xb[3]*v3 + Xb[4]*v4, 0.f);
        const float y4n = fmaxf(bv4 + Xb4[0]*v0 + Xb4[1]*v1 + Xb4[2]*v2 + Xb4[3]*v3 + Xb4[4]*v4, 0.f);
        y = yn; y4 = y4n;
      }
      sm.yst[b4][s_] = y;
      if (s_ == 3) sm.yst[b4][4] = y4;
    }
    // land prefetch into LDS (loads have had the whole phase to complete)
    if (w == 1 && l < 24) sm.ust[nbuf][upb][upc] = pref_u;
    if (w == 2 && l < 8)  sm.dtst[nbuf][l] = pref_dt;
    __syncthreads();
  }

  // epilogue: stores for step KTOT-1
  if (t < 40)                   yo_base[(size_t)(KTOT-1)*5]  = sm.yst[yb][yi];
  else if (t >= 64 && t < 168)  th_base[(size_t)(KTOT-1)*13] = sm.theta[tb][tn];
}

extern "C" void kernel_launch(void* const* d_in, const int* in_sizes, int n_in,
                              void* d_out, int out_size, void* d_ws, size_t ws_size,
                              hipStream_t stream) {
  const float* y0     = (const float*)d_in[0];
  const float* u_seq  = (const float*)d_in[1];
  const float* dt_sq  = (const float*)d_in[2];
  const float* Wl     = (const float*)d_in[3];
  const float* bl     = (const float*)d_in[4];
  const float* W_ih   = (const float*)d_in[5];
  const float* b_ih   = (const float*)d_in[6];
  const float* W_hh   = (const float*)d_in[7];
  const float* b_hh   = (const float*)d_in[8];
  const float* Wh     = (const float*)d_in[9];
  const float* bh     = (const float*)d_in[10];
  const float* jmp    = (const float*)d_in[11];
  float* y_out  = (float*)d_out;
  float* th_out = y_out + (size_t)4096 * KTOT * 5;   // y (B,K,5) then theta (B,K,13)
  rnn_scan_kernel<<<512, 512, 0, stream>>>(
      y0, u_seq, dt_sq, Wl, bl, W_ih, b_ih, W_hh, b_hh, Wh, bh, jmp, y_out, th_out);
}

// Round 6
// 1373.637 us; speedup vs baseline: 4.4467x; 1.9339x over previous
//
#include <hip/hip_runtime.h>
#include <cstdint>
#include <cstddef>

// SimpleRNN: B=4096, K=512, U=3, P=5, LIFT=32, HID=128, NSUB=10
// Round 9: chain-shortening. Round-5 proved per-step chain time is batch-width
// independent (BB=8 chain 2.59us/step vs BB=16 2.81us/step) -> occupancy is a
// dead end (work fixed at 256 CU x 16 batches); only shortening L pays.
// Bottom-up L ~= 2200 cyc vs measured 6734: prime suspect = per-step barrier
// vmcnt(0) drains of 288 scattered 4B global stores issued in GATE.
//  - Output stores -> double-buffered LDS ring (16 steps/half, +36KB LDS, free
//    at 1 block/CU), flushed every 16 steps as coalesced f32x4 by waves 1-7
//    DURING wave0's RK4 tail (their idle bubble). Barriers drain ~nothing.
//  - RK4 substep: balanced fma tree (depth ~18 vs ~30) x 10 serial substeps.
//  - theta lives in the ring (RK4 reads it back same-wave, as before).
// Base otherwise = round-2 kernel (1437 us): BB=16, grid 256, 8 waves.

#define KTOT 512
#define BB   16

typedef _Float16 half8 __attribute__((ext_vector_type(8)));
typedef float    f32x4 __attribute__((ext_vector_type(4)));

struct __align__(16) Smem {
  _Float16 hf16[BB][136];        // f16 hidden (A-frag source)       4352 B
  _Float16 xls[BB][32];          // f16 lift output (A-frag source)  1024 B
  float yring[2][BB][16][5];     // [half][b][kmod][state]          10240 B
  float thring[2][BB][16][13];   // [half][b][kmod][param]          26624 B
  float brz[256];                // b_ih + b_hh for r,z
  float bnx[128];                // b_ih n-gate
  float bnh[128];                // b_hh n-gate
  float bhv[16];
  float yst[BB][8];
  float ust[2][BB][4];           // double-buffered u
  float dtst[2][BB];             // double-buffered dt
};

__device__ __forceinline__ float sigm(float x)     { return 1.f / (1.f + __expf(-x)); }
__device__ __forceinline__ float tanhfast(float x) { return 1.f - 2.f / (1.f + __expf(2.f * x)); }

template<int CTRL>
__device__ __forceinline__ float dppf(float x) {
  return __int_as_float(__builtin_amdgcn_mov_dpp(__float_as_int(x), CTRL, 0xf, 0xf, true));
}
#define QP_PLUS  0x39   // quad_perm [1,2,3,0]
#define QP_MINUS 0x93   // quad_perm [3,0,1,2]
#define QB0 0x00
#define QB1 0x55
#define QB2 0xAA
#define QB3 0xFF

// Y = I + ALPHA * Z * X   (row-per-lane; lane3 also owns row4 in X4r/Y4r)
#define MATMUL(Yr, Y4r, Xr, X4r, ALPHA) do {                                  \
  float xm_[5], xp_[5];                                                       \
  _Pragma("unroll")                                                           \
  for (int j_ = 0; j_ < 5; j_++) {                                            \
    xm_[j_] = dppf<QP_MINUS>(Xr[j_]);                                         \
    xp_[j_] = dppf<QP_PLUS >(Xr[j_]);                                         \
  }                                                                           \
  _Pragma("unroll")                                                           \
  for (int j_ = 0; j_ < 5; j_++) {                                            \
    const float ac_ = Zl*xm_[j_] + Zd*Xr[j_] + Zu*xp_[j_] + Zu4*X4r[j_];      \
    const float a4_ = Z43*Xr[j_] + Z44*X4r[j_];                               \
    Yr[j_]  = ((j_ == s_) ? 1.f : 0.f) + (ALPHA)*ac_;                         \
    Y4r[j_] = ((j_ == 4 ) ? 1.f : 0.f) + (ALPHA)*a4_;                         \
  } } while (0)

__global__ __launch_bounds__(512, 2) void rnn_scan_kernel(
    const float* __restrict__ y0,    const float* __restrict__ u_seq,
    const float* __restrict__ dt_sq, const float* __restrict__ Wl,
    const float* __restrict__ bl,    const float* __restrict__ W_ih,
    const float* __restrict__ b_ih,  const float* __restrict__ W_hh,
    const float* __restrict__ b_hh,  const float* __restrict__ Wh,
    const float* __restrict__ bh,    const float* __restrict__ jmp,
    float* __restrict__ y_out, float* __restrict__ th_out)
{
  __shared__ Smem sm;
  const int t   = threadIdx.x;
  const int w   = t >> 6;          // 0..7
  const int l   = t & 63;
  const int n16 = l & 15;
  const int q   = l >> 4;
  const int B0  = blockIdx.x * BB;

  // ---------------- one-time init ----------------
  if (t < 256) sm.brz[t] = b_ih[t] + b_hh[t];
  if (t < 128) { sm.bnx[t] = b_ih[256+t]; sm.bnh[t] = b_hh[256+t]; }
  if (t < 16)  sm.bhv[t] = (t < 13) ? bh[t] : 0.f;
  if (t >= 256 && t < 384) { const int b = (t-256) >> 3, i = (t-256) & 7;
    sm.yst[b][i] = (i < 5) ? (y0[(size_t)(B0+b)*5 + i] + 0.01f) : 0.f; }
  if (t >= 384 && t < 432) { const int idx = t-384, b = idx/3, c = idx - (idx/3)*3;
    sm.ust[0][b][c] = u_seq[((size_t)(B0+b)*KTOT + 0)*3 + c]; }
  if (t >= 432 && t < 448) sm.dtst[0][t-432] = dt_sq[(size_t)(B0+(t-432))*KTOT + 0];

  // lift: one output per thread; Wl column pinned in VGPRs (loop-invariant)
  const int lb = t >> 5;           // batch 0..15
  const int lo = t & 31;           // lift out col 0..31
  float wlc[8];
  #pragma unroll
  for (int c = 0; c < 8; c++) wlc[c] = Wl[lo*8 + c];
  const float blv = bl[lo];

  // head B-frags (wave0 use)
  half8 whf[4];
  #pragma unroll
  for (int ks = 0; ks < 4; ks++)
    #pragma unroll
    for (int i = 0; i < 8; i++) {
      const int kk = ks*32 + q*8 + i;
      whf[ks][i] = (n16 < 13) ? (_Float16)Wh[n16*128 + kk] : (_Float16)0.f;
    }

  // GRU weight fragments: this wave's single 16-col slice
  const int jR = w*16 + n16;
  const int jZ = jR + 128, jN = jR + 256;
  half8 wihR, wihZ, wihN, whhR[4], whhZ[4], whhN[4];
  #pragma unroll
  for (int i = 0; i < 8; i++) {
    const int kk = q*8 + i;
    wihR[i] = (_Float16)W_ih[jR*32 + kk];
    wihZ[i] = (_Float16)W_ih[jZ*32 + kk];
    wihN[i] = (_Float16)W_ih[jN*32 + kk];
  }
  #pragma unroll
  for (int ks = 0; ks < 4; ks++)
    #pragma unroll
    for (int i = 0; i < 8; i++) {
      const int kk = ks*32 + q*8 + i;
      whhR[ks][i] = (_Float16)W_hh[jR*128 + kk];
      whhZ[ks][i] = (_Float16)W_hh[jZ*128 + kk];
      whhN[ks][i] = (_Float16)W_hh[jN*128 + kk];
    }

  float hreg[4] = {0.f, 0.f, 0.f, 0.f};
  const f32x4 zero4 = {0.f, 0.f, 0.f, 0.f};
  f32x4 accPreR = zero4, accPreZ = zero4, accPreN = zero4;   // h-GEMM partials

  // RK4 lane mapping (wave0): lane = b4*4 + s_, row4 state on s_==3
  const int s_ = l & 3, b4 = l >> 2;
  const float jr0 = jmp[0*5 + s_], jr1 = jmp[1*5 + s_], jr2 = jmp[2*5 + s_];
  const float j40 = (s_==3) ? jmp[4]  : 0.f;
  const float j41 = (s_==3) ? jmp[9]  : 0.f;
  const float j42 = (s_==3) ? jmp[14] : 0.f;

  // u-prefetch mapping (wave1)
  const int upb = l/3, upc = l - (l/3)*3;             // l < 48

  __syncthreads();

  // hoist loop-invariant LDS biases into registers (legal: after the init barrier)
  const float br  = sm.brz[jR];
  const float bz  = sm.brz[128 + jR];
  const float bx  = sm.bnx[jR];
  const float bn  = sm.bnh[jR];
  const float bb_ = sm.bhv[n16];

  #pragma unroll 1
  for (int k = 0; k < KTOT; k++) {
    const int buf  = k & 1;
    const int nbuf = (k + 1) & 1;
    const int kp   = (k + 1 < KTOT) ? (k + 1) : (KTOT - 1);

    // ---- phase LIFT: one silu(feat.Wl) value per thread ----
    {
      const f32x4 uu = *(const f32x4*)&sm.ust[buf][lb][0];
      const f32x4 ya = *(const f32x4*)&sm.yst[lb][0];
      const f32x4 yc = *(const f32x4*)&sm.yst[lb][4];
      const float a = blv
        + uu[0]*wlc[0] + uu[1]*wlc[1] + uu[2]*wlc[2]
        + ya[0]*wlc[3] + ya[1]*wlc[4] + ya[2]*wlc[5] + ya[3]*wlc[6]
        + yc[0]*wlc[7];
      sm.xls[lb][lo] = (_Float16)(a * sigm(a));
    }
    __syncthreads();

    // ---- phase GATE: x-part MFMAs + activations (no global traffic) ----
    {
      const half8 xf = *(const half8*)&sm.xls[n16][q*8];
      const f32x4 accR  = __builtin_amdgcn_mfma_f32_16x16x32_f16(xf, wihR, accPreR, 0,0,0);
      const f32x4 accZ  = __builtin_amdgcn_mfma_f32_16x16x32_f16(xf, wihZ, accPreZ, 0,0,0);
      const f32x4 accXN = __builtin_amdgcn_mfma_f32_16x16x32_f16(xf, wihN, zero4,   0,0,0);
      #pragma unroll
      for (int rg = 0; rg < 4; rg++) {
        const float r  = sigm(accR[rg] + br);
        const float z  = sigm(accZ[rg] + bz);
        const float nn = tanhfast(accXN[rg] + bx + r*(accPreN[rg] + bn));
        const float ho = hreg[rg];
        const float hn = nn + z*(ho - nn);
        hreg[rg] = hn;
        sm.hf16[q*4 + rg][jR] = (_Float16)hn;
      }
    }
    __syncthreads();

    // ---- phase CD: h-GEMM for step k+1  ||  wave0: head + theta + RK4
    //      || waves1-7: ring flush of steps k-16..k-1 (hides in wave0 tail) ----
    float pref_u = 0.f, pref_dt = 0.f;
    if (w == 1 && l < 48)
      pref_u = u_seq[((size_t)(B0 + upb)*KTOT + kp)*3 + upc];
    if (w == 2 && l < 16)
      pref_dt = dt_sq[(size_t)(B0 + l)*KTOT + kp];

    half8 hfrag[4];
    #pragma unroll
    for (int ks = 0; ks < 4; ks++)
      hfrag[ks] = *(const half8*)&sm.hf16[n16][ks*32 + q*8];

    accPreR = zero4; accPreZ = zero4; accPreN = zero4;
    #pragma unroll
    for (int ks = 0; ks < 4; ks++) {
      accPreR = __builtin_amdgcn_mfma_f32_16x16x32_f16(hfrag[ks], whhR[ks], accPreR, 0,0,0);
      accPreZ = __builtin_amdgcn_mfma_f32_16x16x32_f16(hfrag[ks], whhZ[ks], accPreZ, 0,0,0);
      accPreN = __builtin_amdgcn_mfma_f32_16x16x32_f16(hfrag[ks], whhN[ks], accPreN, 0,0,0);
    }

    if (w == 0) {
      const int km = k & 15, hh = (k >> 4) & 1;
      // head -> theta (into ring; RK4 reads it back same-wave, LDS-ordered)
      f32x4 accH = zero4;
      #pragma unroll
      for (int ks = 0; ks < 4; ks++)
        accH = __builtin_amdgcn_mfma_f32_16x16x32_f16(hfrag[ks], whf[ks], accH, 0,0,0);
      #pragma unroll
      for (int rg = 0; rg < 4; rg++) {
        const float sg  = sigm(accH[rg] + bb_);
        const float thv = (n16 < 8) ? (0.01f + 2.99f*sg) : (0.3f*sg);
        if (n16 < 13) sm.thring[hh][q*4 + rg][km][n16] = thv;
      }
      // ---- exact-linear RK4 ----
      const float* th = &sm.thring[hh][b4][km][0];
      const float dt = sm.dtst[buf][b4];
      const float h  = dt * 0.1f;
      const float thm = th[s_ ? (s_ - 1) : 0];
      const float Zl  = s_ ? h*thm : 0.f;
      const float krs = s_ ? th[3 + s_] : 0.f;
      const float Zd  = -h*(th[s_] + krs);
      const float Zur = h*th[4 + s_];
      const float Zu  = (s_ < 3) ? Zur : 0.f;
      const float Zu4 = (s_ == 3) ? Zur : 0.f;
      const float Z43 = h*th[3];
      const float Z44 = -h*th[7];
      const float c0 = th[8], c1 = th[9], c2 = th[10], c3 = th[11], c4 = th[12];
      float Xa[5], Xa4[5], Xb[5], Xb4[5];
      #pragma unroll
      for (int j = 0; j < 5; j++) {
        const float zr = (j == s_) ? Zd : ((j == s_ + 1) ? Zur : ((j + 1 == s_) ? Zl : 0.f));
        Xa[j] = ((j == s_) ? 1.f : 0.f) + 0.25f*zr;
      }
      Xa4[0] = 0.f; Xa4[1] = 0.f; Xa4[2] = 0.f;
      Xa4[3] = 0.25f*Z43; Xa4[4] = 1.f + 0.25f*Z44;
      MATMUL(Xb, Xb4, Xa, Xa4, (1.f/3.f));   // X2 = I + (Z/3) X1
      MATMUL(Xa, Xa4, Xb, Xb4, 0.5f);        // X3 = S = I + (Z/2) X2
      const float bv  = h*(Xa[0]*c0 + Xa[1]*c1 + Xa[2]*c2 + Xa[3]*c3 + Xa[4]*c4);
      const float bv4 = h*(Xa4[0]*c0 + Xa4[1]*c1 + Xa4[2]*c2 + Xa4[3]*c3 + Xa4[4]*c4);
      MATMUL(Xb, Xb4, Xa, Xa4, 1.f);         // A = I + Z S
      const float uu0 = sm.ust[buf][b4][0], uu1 = sm.ust[buf][b4][1], uu2 = sm.ust[buf][b4][2];
      float y  = sm.yst[b4][s_] + uu0*jr0 + uu1*jr1 + uu2*jr2;
      float y4 = sm.yst[b4][4]  + uu0*j40 + uu1*j41 + uu2*j42;
      // 10 substeps, balanced reduction tree (depth ~18 vs 30)
      #pragma unroll
      for (int ss = 0; ss < 10; ss++) {
        const float v0 = dppf<QB0>(y), v1 = dppf<QB1>(y),
                    v2 = dppf<QB2>(y), v3 = dppf<QB3>(y);
        const float v4 = dppf<QB3>(y4);
        const float a1 = fmaf(Xb[0],  v0, bv);
        const float a2 = fmaf(Xb[2],  v2, Xb[1]*v1);
        const float a3 = fmaf(Xb[4],  v4, Xb[3]*v3);
        const float b1 = fmaf(Xb4[0], v0, bv4);
        const float b2 = fmaf(Xb4[2], v2, Xb4[1]*v1);
        const float b3 = fmaf(Xb4[4], v4, Xb4[3]*v3);
        const float yn  = fmaxf(a1 + (a2 + a3), 0.f);
        const float y4n = fmaxf(b1 + (b2 + b3), 0.f);
        y = yn; y4 = y4n;
      }
      sm.yst[b4][s_] = y;
      sm.yring[hh][b4][km][s_] = y;
      if (s_ == 3) { sm.yst[b4][4] = y4; sm.yring[hh][b4][km][4] = y4; }
    } else {
      // ---- ring flush: steps k-16..k-1, coalesced f32x4, waves 1-7 only ----
      if ((k & 15) == 0 && k >= 16) {
        const int hf = ((k >> 4) & 1) ^ 1;
        const int kb = k - 16;
        const int idx = t - 64;                  // 0..447
        #pragma unroll
        for (int rep = 0; rep < 3; rep++) {
          const int o = idx + rep*448;
          if (o < 1152) {
            if (o < 320) {
              const int b = o/20, j = o - b*20;
              *(f32x4*)&y_out[((size_t)(B0 + b)*KTOT + kb)*5 + j*4] =
                  *(const f32x4*)((const float*)&sm.yring[hf][b][0][0] + j*4);
            } else {
              const int o2 = o - 320;
              const int b = o2/52, j = o2 - b*52;
              *(f32x4*)&th_out[((size_t)(B0 + b)*KTOT + kb)*13 + j*4] =
                  *(const f32x4*)((const float*)&sm.thring[hf][b][0][0] + j*4);
            }
          }
        }
      }
    }
    // land prefetch into LDS (loads have had the whole phase to complete)
    if (w == 1 && l < 48) sm.ust[nbuf][upb][upc] = pref_u;
    if (w == 2 && l < 16) sm.dtst[nbuf][l] = pref_dt;
    __syncthreads();
  }

  // epilogue: flush the last 16 steps (half 1, steps 496..511), all threads
  {
    const int kb = KTOT - 16;
    const int hf = ((KTOT >> 4) & 1) ^ 1;   // = 1
    #pragma unroll
    for (int rep = 0; rep < 3; rep++) {
      const int o = t + rep*512;
      if (o < 1152) {
        if (o < 320) {
          const int b = o/20, j = o - b*20;
          *(f32x4*)&y_out[((size_t)(B0 + b)*KTOT + kb)*5 + j*4] =
              *(const f32x4*)((const float*)&sm.yring[hf][b][0][0] + j*4);
        } else {
          const int o2 = o - 320;
          const int b = o2/52, j = o2 - b*52;
          *(f32x4*)&th_out[((size_t)(B0 + b)*KTOT + kb)*13 + j*4] =
              *(const f32x4*)((const float*)&sm.thring[hf][b][0][0] + j*4);
        }
      }
    }
  }
}

extern "C" void kernel_launch(void* const* d_in, const int* in_sizes, int n_in,
                              void* d_out, int out_size, void* d_ws, size_t ws_size,
                              hipStream_t stream) {
  const float* y0     = (const float*)d_in[0];
  const float* u_seq  = (const float*)d_in[1];
  const float* dt_sq  = (const float*)d_in[2];
  const float* Wl     = (const float*)d_in[3];
  const float* bl     = (const float*)d_in[4];
  const float* W_ih   = (const float*)d_in[5];
  const float* b_ih   = (const float*)d_in[6];
  const float* W_hh   = (const float*)d_in[7];
  const float* b_hh   = (const float*)d_in[8];
  const float* Wh     = (const float*)d_in[9];
  const float* bh     = (const float*)d_in[10];
  const float* jmp    = (const float*)d_in[11];
  float* y_out  = (float*)d_out;
  float* th_out = y_out + (size_t)4096 * KTOT * 5;   // y (B,K,5) then theta (B,K,13)
  rnn_scan_kernel<<<256, 512, 0, stream>>>(
      y0, u_seq, dt_sq, Wl, bl, W_ih, b_ih, W_hh, b_hh, Wh, bh, jmp, y_out, th_out);
}